// Round 5
// baseline (303.964 us; speedup 1.0000x reference)
//
#include <hip/hip_runtime.h>
#include <stdint.h>

#define NN   40000
#define RR   16
#define EE   50000
#define DD   256
#define NB   4
#define KTOT (NB*DD + DD)   // 1280
#define BM   128
#define BN   128
#define BK   32
#define NITER (KTOT/BK)     // 40

#define SCAN_BLK  40
#define SCAN_ELEM 1024      // elements per scan block (40*1024 >= NN)

#define GATHER_BLKS 2048    // persistent: 8 blocks/CU x 256 CUs
#define NWAVES (GATHER_BLKS * 4)

typedef __bf16 bf16x8 __attribute__((ext_vector_type(8)));
typedef float  f32x4  __attribute__((ext_vector_type(4)));
typedef float  f32x2  __attribute__((ext_vector_type(2)));
typedef unsigned short ushort_t;
typedef unsigned short u16x4 __attribute__((ext_vector_type(4)));

__device__ inline unsigned short f2bf(float f) {
    unsigned int b = __builtin_bit_cast(unsigned int, f);
    b += 0x7FFFu + ((b >> 16) & 1u);      // round-to-nearest-even
    return (unsigned short)(b >> 16);
}

// direct global->LDS DMA, 16B per lane. LDS dest must be wave-uniform base
// (+ lane*16 implicit). AS casts via integer round-trip (LDS aperture is
// 2^32-aligned, low 32 bits == LDS offset).
__device__ __forceinline__ void gll16(const void* g, void* l) {
    __builtin_amdgcn_global_load_lds(
        (__attribute__((address_space(1))) void*)(uintptr_t)g,
        (__attribute__((address_space(3))) void*)(uint32_t)(uintptr_t)l,
        16, 0, 0);
}

// ws layout (bytes), all 16B-aligned:
//   vb      @ 0            NN*1024 bf16 =  81,920,000
//   xb      @ 81,920,000   NN*256  bf16 =  20,480,000
//   Bt      @ 102,400,000  256*1280 bf16 =    655,360
//   deg     @ 103,055,360  NN*RR int    =   2,560,000   [node-major: deg[n*RR+r]]
//   offsets @ 105,775,360  (NN+1) int
//   cursor  @ 105,935,376  NN int
//   recs    @ 106,095,376  RR*EE u32    =   3,200,000
//   bsum    @ 109,295,376  SCAN_BLK int

#define CAST_BLKS ((NN * DD / 4 + DD * KTOT + 255) / 256)   // 11280
#define DEG_BLKS  ((RR * EE + 255) / 256)                   // 3125

// fused: xb cast + Bt build + per-relation degree histogram
__global__ __launch_bounds__(256) void k_prep(const float* __restrict__ x,
                                              const float* __restrict__ bases,
                                              const float* __restrict__ lw,
                                              const int* __restrict__ edst,
                                              ushort_t* __restrict__ xb,
                                              ushort_t* __restrict__ Bt,
                                              int* __restrict__ deg) {
    int b = blockIdx.x;
    if (b < CAST_BLKS) {
        int t = b * 256 + threadIdx.x;
        const int NX = NN * DD / 4;
        if (t < NX) {
            float4 f = *(const float4*)(x + (size_t)t * 4);
            ushort4 o;
            o.x = f2bf(f.x); o.y = f2bf(f.y); o.z = f2bf(f.z); o.w = f2bf(f.w);
            *(ushort4*)(xb + (size_t)t * 4) = o;
        } else {
            int u = t - NX;                // u = o*1280 + k
            if (u < DD * KTOT) {
                int o = u / KTOT, k = u - o * KTOT;
                float f = (k < NB * DD) ? bases[(size_t)k * DD + o]
                                        : lw[(size_t)(k - NB * DD) * DD + o];
                Bt[u] = f2bf(f);
            }
        }
    } else {
        int e = (b - CAST_BLKS) * 256 + threadIdx.x;
        if (e < RR * EE) {
            int r = e / EE;
            atomicAdd(&deg[(size_t)edst[e] * RR + r], 1);   // node-major layout
        }
    }
}

// phase A: per-node degree sum (node-major deg: 4 int4 per node) +
// block-local exclusive scan
__global__ __launch_bounds__(256) void k_scanA(const int* __restrict__ deg,
                                               int* __restrict__ offsets,
                                               int* __restrict__ bsum) {
    __shared__ int part[256];
    int t = threadIdx.x, b = blockIdx.x;
    int g = b * SCAN_ELEM + t * 4;
    int hh[4] = {0, 0, 0, 0};
    if (g < NN) {                          // NN%4==0 so g<NN implies g+3<NN
#pragma unroll
        for (int i = 0; i < 4; i++) {
            const int4* dp = (const int4*)(deg + (size_t)(g + i) * RR);
            int4 d0 = dp[0], d1 = dp[1], d2 = dp[2], d3 = dp[3];
            hh[i] = d0.x + d0.y + d0.z + d0.w + d1.x + d1.y + d1.z + d1.w
                  + d2.x + d2.y + d2.z + d2.w + d3.x + d3.y + d3.z + d3.w;
        }
    }
    int s = hh[0] + hh[1] + hh[2] + hh[3];
    part[t] = s;
    __syncthreads();
    for (int off = 1; off < 256; off <<= 1) {
        int v = (t >= off) ? part[t - off] : 0;
        __syncthreads();
        part[t] += v;
        __syncthreads();
    }
    int ex = part[t] - s;
    if (g < NN) {
        int4 o;
        o.x = ex;
        o.y = ex + hh[0];
        o.z = ex + hh[0] + hh[1];
        o.w = ex + hh[0] + hh[1] + hh[2];
        *(int4*)(offsets + g) = o;
    }
    if (t == 255) bsum[b] = part[255];
}

// phase B: add block-prefix base, mirror into cursor, write offsets[NN]
__global__ __launch_bounds__(256) void k_scanB(const int* __restrict__ bsum,
                                               int* __restrict__ offsets,
                                               int* __restrict__ cursor) {
    __shared__ int sbase, stot;
    int t = threadIdx.x, b = blockIdx.x;
    if (t == 0) {
        int acc = 0, base = 0;
        for (int i = 0; i < SCAN_BLK; i++) {
            if (i == b) base = acc;
            acc += bsum[i];
        }
        sbase = base;
        stot = acc;
    }
    __syncthreads();
    int base = sbase;
    int g = b * SCAN_ELEM + t * 4;
    if (g < NN) {
        int4 o = *(const int4*)(offsets + g);
        o.x += base; o.y += base; o.z += base; o.w += base;
        *(int4*)(offsets + g) = o;
        *(int4*)(cursor + g) = o;
    }
    if (b == SCAN_BLK - 1 && t == 0) offsets[NN] = stot;
}

__global__ __launch_bounds__(256) void k_escatter(const int* __restrict__ esrc,
                                                  const int* __restrict__ edst,
                                                  int* __restrict__ cursor,
                                                  unsigned int* __restrict__ recs) {
    int e = blockIdx.x * blockDim.x + threadIdx.x;
    if (e >= RR * EE) return;
    int r = e / EE;
    int d = edst[e];
    int pos = atomicAdd(&cursor[d], 1);
    recs[pos] = (unsigned int)esrc[e] | ((unsigned int)r << 16);
}

// persistent waves, 8-edge batches, all 2048 blocks co-resident (256,8).
// Tail edges clamp their recs index to end-1 and read the ZERO weight slot
// (wtab[wv][64..67]=0) -> no serial chained tail. beg/end scalarized
// (readfirstlane) so batch indexing + mask select are SALU / uniform-address
// loads. Next-node metadata prefetched before the edge loop. vb stores
// non-temporal (write-once stream; keep xb in L2).
__global__ __launch_bounds__(256, 8) void k_gather(const ushort_t* __restrict__ xb,
                                                   const float* __restrict__ coeff,
                                                   const int* __restrict__ deg,
                                                   const int* __restrict__ offsets,
                                                   const unsigned int* __restrict__ recs,
                                                   ushort_t* __restrict__ vb) {
    __shared__ float wtab[4][72];          // [64..67] = zero slot (16B aligned)
    int lane = threadIdx.x & 63;
    int wv   = threadIdx.x >> 6;
    int gw   = __builtin_amdgcn_readfirstlane(blockIdx.x * 4 + wv);

    if (lane < 8) wtab[wv][64 + lane] = 0.0f;

    const ushort_t* xl = xb + lane * 4;
    const float* wrow = &wtab[wv][0];
    float cf = coeff[lane];
    int rsel = lane >> 2;

    int n = gw;
    int off0 = 0, off1 = 0, dgc = 0;
    if (n < NN) {
        off0 = offsets[n];
        off1 = offsets[n + 1];
        dgc  = deg[(size_t)n * RR + rsel];
    }

    for (; n < NN; ) {
        int nn = n + NWAVES;
        int beg = __builtin_amdgcn_readfirstlane(off0);
        int end = __builtin_amdgcn_readfirstlane(off1);
        {   // wtab[wv][r*4+b] = coeff[r*4+b] / max(deg[n][r],1)
            float inv = 1.0f / (float)(dgc > 0 ? dgc : 1);
            wtab[wv][lane] = cf * inv;
        }
        if (nn < NN) {   // prefetch next node metadata
            off0 = offsets[nn];
            off1 = offsets[nn + 1];
            dgc  = deg[(size_t)nn * RR + rsel];
        }

        f32x2 a[4][2];
#pragma unroll
        for (int b = 0; b < 4; b++) { a[b][0] = (f32x2){0,0}; a[b][1] = (f32x2){0,0}; }

        int end1 = end - 1;
        for (int ei = beg; ei < end; ei += 8) {
            int cnt = end - ei;            // scalar
            unsigned int rr[8];
#pragma unroll
            for (int k = 0; k < 8; k++) {
                int ii = ei + k; if (ii > end1) ii = end1;
                rr[k] = recs[ii];
            }
            uint2 u[8];
#pragma unroll
            for (int k = 0; k < 8; k++)
                u[k] = *(const uint2*)(xl + (unsigned)((rr[k] & 0xFFFFu) * DD));
#pragma unroll
            for (int k = 0; k < 8; k++) {
                int widx = (k < cnt) ? (int)((rr[k] >> 16) * 4) : 64;
                float4 w = *(const float4*)&wrow[widx];
                f32x2 lo, hi;
                lo.x = __builtin_bit_cast(float, u[k].x << 16);
                lo.y = __builtin_bit_cast(float, u[k].x & 0xFFFF0000u);
                hi.x = __builtin_bit_cast(float, u[k].y << 16);
                hi.y = __builtin_bit_cast(float, u[k].y & 0xFFFF0000u);
                a[0][0] = lo * (f32x2){w.x, w.x} + a[0][0];
                a[0][1] = hi * (f32x2){w.x, w.x} + a[0][1];
                a[1][0] = lo * (f32x2){w.y, w.y} + a[1][0];
                a[1][1] = hi * (f32x2){w.y, w.y} + a[1][1];
                a[2][0] = lo * (f32x2){w.z, w.z} + a[2][0];
                a[2][1] = hi * (f32x2){w.z, w.z} + a[2][1];
                a[3][0] = lo * (f32x2){w.w, w.w} + a[3][0];
                a[3][1] = hi * (f32x2){w.w, w.w} + a[3][1];
            }
        }

        ushort_t* vr = vb + (size_t)n * (NB * DD) + lane * 4;
#pragma unroll
        for (int b = 0; b < 4; b++) {
            u16x4 o;
            o.x = f2bf(a[b][0].x); o.y = f2bf(a[b][0].y);
            o.z = f2bf(a[b][1].x); o.w = f2bf(a[b][1].y);
            __builtin_nontemporal_store(o, (u16x4*)(vr + b * DD));
        }
        n = nn;
    }
}

// MFMA GEMM: out[40000][256] = relu([vb | xb] @ Bt^T + bias)
// 128x128 block tile (grid 2x313, col-fastest -> A re-read L2-hot), 4 waves
// each 64x64 (4x4 frags of 16x16x32), staged via global_load_lds width-16.
// THREE rotating LDS buffers, staged 2 tiles ahead; per-iteration wait is
// s_waitcnt vmcnt(4) -- retires only the OLDEST stage (issued 2 compute
// phases earlier, latency fully hidden) and leaves the newest 4 loads in
// flight across the barrier (T4: counted vmcnt, never 0 in the loop).
// WAR safe: buffer overwritten at it+2 was last read before the barrier at
// the end of iteration it-1. Epilogue: vmcnt(0) at it=NITER-2, none after.
// Bank-conflict swizzle chunk' = q ^ ((row>>2)&3) applied by pre-swizzling
// the per-lane GLOBAL source chunk (LDS dest stays linear for the DMA).
__global__ __launch_bounds__(256) void k_gemm(const ushort_t* __restrict__ vb,
                                              const ushort_t* __restrict__ xb,
                                              const ushort_t* __restrict__ Bt,
                                              const float* __restrict__ bias,
                                              float* __restrict__ out) {
    __shared__ __align__(16) ushort_t As[3][BM * BK];   // 3 x 8 KB
    __shared__ __align__(16) ushort_t Bs[3][BN * BK];   // 3 x 8 KB
    int tid  = threadIdx.x;
    int lane = tid & 63;
    int w    = tid >> 6;
    int wr   = w >> 1, wc = w & 1;     // wave tile: rows wr*64.., cols wc*64..
    int rowbase = blockIdx.y * BM;     // 313*128 = 40064: tail rows clamped
    int nbase   = blockIdx.x * BN;
    int ml = lane & 15, q = lane >> 4;

    // staging: thread t covers LDS slot (row = t>>2, chunk = t&3); source
    // chunk pre-swizzled g = (t&3) ^ ((row>>2)&3)  [(t>>4)&3 == (srow>>2)&3]
    int srow  = tid >> 2;
    int g     = (tid & 3) ^ ((tid >> 4) & 3);
    int wbase = __builtin_amdgcn_readfirstlane(w << 10);   // wave base within 4KB round

    int arow0 = rowbase + srow;       if (arow0 >= NN) arow0 = NN - 1;
    int arow1 = rowbase + 64 + srow;  if (arow1 >= NN) arow1 = NN - 1;
    const ushort_t* pvA0 = vb + (size_t)arow0 * (NB * DD) + g * 8;
    const ushort_t* pvA1 = vb + (size_t)arow1 * (NB * DD) + g * 8;
    const ushort_t* pxA0 = xb + (size_t)arow0 * DD + g * 8;
    const ushort_t* pxA1 = xb + (size_t)arow1 * DD + g * 8;
    const ushort_t* pB0  = Bt + (size_t)(nbase + srow) * KTOT + g * 8;
    const ushort_t* pB1  = Bt + (size_t)(nbase + 64 + srow) * KTOT + g * 8;

    f32x4 acc[4][4];
#pragma unroll
    for (int i = 0; i < 4; i++)
#pragma unroll
        for (int j = 0; j < 4; j++) acc[i][j] = (f32x4){0, 0, 0, 0};

    // fragment read offsets (swizzled, ushort units)
    int aoff[4], boff[4];
#pragma unroll
    for (int i = 0; i < 4; i++) {
        int m = wr * 64 + i * 16 + ml;
        aoff[i] = m * BK + ((q ^ ((m >> 2) & 3)) * 8);
    }
#pragma unroll
    for (int j = 0; j < 4; j++) {
        int n = wc * 64 + j * 16 + ml;
        boff[j] = n * BK + ((q ^ ((n >> 2) & 3)) * 8);
    }

    auto stage = [&](int s, int kb) {
        const ushort_t* a0 = (kb < NB * DD) ? pvA0 + kb : pxA0 + (kb - NB * DD);
        const ushort_t* a1 = (kb < NB * DD) ? pvA1 + kb : pxA1 + (kb - NB * DD);
        char* ab = (char*)&As[s][0] + wbase;
        char* bb = (char*)&Bs[s][0] + wbase;
        gll16(a0,       ab);           // A rows   0..63  of tile
        gll16(a1,       ab + 4096);    // A rows  64..127
        gll16(pB0 + kb, bb);           // B rows   0..63
        gll16(pB1 + kb, bb + 4096);    // B rows  64..127
    };

    // prologue: stage tiles 0 and 1; wait for tile 0 only (tile 1 in flight)
    stage(0, 0);
    stage(1, BK);
    asm volatile("s_waitcnt vmcnt(4)" ::: "memory");
    __syncthreads();

    int cur = 0;
    for (int it = 0; it < NITER; ++it) {
        int s2 = it + 2 < 3 ? it + 2 : (it + 2) - ((it + 2) / 3) * 3; // (it+2)%3
        if (it + 2 < NITER) stage(s2, (it + 2) * BK);   // 2-ahead into free buf
        bf16x8 af[4], bf[4];
#pragma unroll
        for (int i = 0; i < 4; i++) af[i] = *(const bf16x8*)&As[cur][aoff[i]];
#pragma unroll
        for (int j = 0; j < 4; j++) bf[j] = *(const bf16x8*)&Bs[cur][boff[j]];
#pragma unroll
        for (int i = 0; i < 4; i++)
#pragma unroll
            for (int j = 0; j < 4; j++)
                acc[i][j] = __builtin_amdgcn_mfma_f32_16x16x32_bf16(af[i], bf[j], acc[i][j], 0, 0, 0);
        if (it + 2 < NITER) {
            asm volatile("s_waitcnt vmcnt(4)" ::: "memory");  // oldest stage done
        } else if (it + 1 < NITER) {
            asm volatile("s_waitcnt vmcnt(0)" ::: "memory");  // drain last stage
        }
        __syncthreads();
        cur = cur + 1 < 3 ? cur + 1 : 0;
    }

    // epilogue: C layout col=lane&15, row=(lane>>4)*4+reg; predicate M-tail
#pragma unroll
    for (int i = 0; i < 4; i++) {
#pragma unroll
        for (int r = 0; r < 4; r++) {
            int ng = rowbase + wr * 64 + i * 16 + q * 4 + r;
            if (ng < NN) {
#pragma unroll
                for (int j = 0; j < 4; j++) {
                    int o = nbase + wc * 64 + j * 16 + ml;
                    float vv = acc[i][j][r] + bias[o];
                    out[(size_t)ng * DD + o] = fmaxf(vv, 0.0f);
                }
            }
        }
    }
}

extern "C" void kernel_launch(void* const* d_in, const int* in_sizes, int n_in,
                              void* d_out, int out_size, void* d_ws, size_t ws_size,
                              hipStream_t stream) {
    const float* x     = (const float*)d_in[0];
    const float* bases = (const float*)d_in[1];
    const float* coeff = (const float*)d_in[2];
    const float* lw    = (const float*)d_in[3];
    const float* bias  = (const float*)d_in[4];
    const int*   esrc  = (const int*)d_in[5];
    const int*   edst  = (const int*)d_in[6];
    float* out = (float*)d_out;

    char* ws = (char*)d_ws;
    ushort_t*     vb      = (ushort_t*)(ws);
    ushort_t*     xb      = (ushort_t*)(ws + 81920000);
    ushort_t*     Bt      = (ushort_t*)(ws + 102400000);
    int*          deg     = (int*)(ws + 103055360);
    int*          offsets = (int*)(ws + 105775360);
    int*          cursor  = (int*)(ws + 105935376);
    unsigned int* recs    = (unsigned int*)(ws + 106095376);
    int*          bsum    = (int*)(ws + 109295376);

    hipMemsetAsync(deg, 0, (size_t)RR * NN * sizeof(int), stream);

    int ne = RR * EE;
    k_prep<<<CAST_BLKS + DEG_BLKS, 256, 0, stream>>>(x, bases, lw, edst, xb, Bt, deg);
    k_scanA<<<SCAN_BLK, 256, 0, stream>>>(deg, offsets, bsum);
    k_scanB<<<SCAN_BLK, 256, 0, stream>>>(bsum, offsets, cursor);
    k_escatter<<<(ne + 255) / 256, 256, 0, stream>>>(esrc, edst, cursor, recs);
    k_gather<<<GATHER_BLKS, 256, 0, stream>>>(xb, coeff, deg, offsets, recs, vb);
    dim3 ggrid(DD / BN, (NN + BM - 1) / BM);   // (2, 313), col-block fastest
    k_gemm<<<ggrid, 256, 0, stream>>>(vb, xb, Bt, bias, out);
}

// Round 7
// 286.971 us; speedup vs baseline: 1.0592x; 1.0592x over previous
//
#include <hip/hip_runtime.h>
#include <stdint.h>

#define NN   40000
#define RR   16
#define EE   50000
#define DD   256
#define NB   4
#define KTOT (NB*DD + DD)   // 1280
#define BM   128
#define BN   128
#define BK   32
#define NITER (KTOT/BK)     // 40

#define GEMM_NWG (((NN + BM - 1) / BM) * (DD / BN))   // 313*2 = 626

#define SCAN_BLK  40
#define SCAN_ELEM 1024      // elements per scan block (40*1024 >= NN)

typedef __bf16 bf16x8 __attribute__((ext_vector_type(8)));
typedef float  f32x4  __attribute__((ext_vector_type(4)));
typedef float  f32x2  __attribute__((ext_vector_type(2)));
typedef unsigned short ushort_t;

__device__ inline unsigned short f2bf(float f) {
    unsigned int b = __builtin_bit_cast(unsigned int, f);
    b += 0x7FFFu + ((b >> 16) & 1u);      // round-to-nearest-even
    return (unsigned short)(b >> 16);
}

// direct global->LDS DMA, 16B per lane. LDS dest must be wave-uniform base
// (+ lane*16 implicit). AS casts via integer round-trip (LDS aperture is
// 2^32-aligned, low 32 bits == LDS offset).
__device__ __forceinline__ void gll16(const void* g, void* l) {
    __builtin_amdgcn_global_load_lds(
        (__attribute__((address_space(1))) void*)(uintptr_t)g,
        (__attribute__((address_space(3))) void*)(uint32_t)(uintptr_t)l,
        16, 0, 0);
}

// ws layout (bytes), all 16B-aligned:
//   vb      @ 0            NN*1024 bf16 =  81,920,000
//   xb      @ 81,920,000   NN*256  bf16 =  20,480,000
//   Bt      @ 102,400,000  256*1280 bf16 =    655,360
//   deg     @ 103,055,360  RR*NN int    =   2,560,000   [row-major: deg[r*NN+n]]
//   offsets @ 105,775,360  (NN+1) int
//   cursor  @ 105,935,376  NN int
//   recs    @ 106,095,376  RR*EE u32    =   3,200,000
//   bsum    @ 109,295,376  SCAN_BLK int

#define CAST_BLKS ((NN * DD / 4 + DD * KTOT + 255) / 256)   // 11280
#define DEG_BLKS  ((RR * EE + 255) / 256)                   // 3125

// fused: xb cast + Bt build + per-relation degree histogram
__global__ __launch_bounds__(256) void k_prep(const float* __restrict__ x,
                                              const float* __restrict__ bases,
                                              const float* __restrict__ lw,
                                              const int* __restrict__ edst,
                                              ushort_t* __restrict__ xb,
                                              ushort_t* __restrict__ Bt,
                                              int* __restrict__ deg) {
    int b = blockIdx.x;
    if (b < CAST_BLKS) {
        int t = b * 256 + threadIdx.x;
        const int NX = NN * DD / 4;
        if (t < NX) {
            float4 f = *(const float4*)(x + (size_t)t * 4);
            ushort4 o;
            o.x = f2bf(f.x); o.y = f2bf(f.y); o.z = f2bf(f.z); o.w = f2bf(f.w);
            *(ushort4*)(xb + (size_t)t * 4) = o;
        } else {
            int u = t - NX;                // u = o*1280 + k
            if (u < DD * KTOT) {
                int o = u / KTOT, k = u - o * KTOT;
                float f = (k < NB * DD) ? bases[(size_t)k * DD + o]
                                        : lw[(size_t)(k - NB * DD) * DD + o];
                Bt[u] = f2bf(f);
            }
        }
    } else {
        int e = (b - CAST_BLKS) * 256 + threadIdx.x;
        if (e < RR * EE) {
            int r = e / EE;
            atomicAdd(&deg[r * NN + edst[e]], 1);
        }
    }
}

// phase A: per-node degree sum (from deg directly) + block-local exclusive scan
__global__ __launch_bounds__(256) void k_scanA(const int* __restrict__ deg,
                                               int* __restrict__ offsets,
                                               int* __restrict__ bsum) {
    __shared__ int part[256];
    int t = threadIdx.x, b = blockIdx.x;
    int g = b * SCAN_ELEM + t * 4;
    int4 h = {0, 0, 0, 0};
    if (g < NN) {                          // NN%4==0 so g<NN implies g+3<NN
#pragma unroll
        for (int r = 0; r < RR; r++) {
            int4 d = *(const int4*)(deg + (size_t)r * NN + g);
            h.x += d.x; h.y += d.y; h.z += d.z; h.w += d.w;
        }
    }
    int s = h.x + h.y + h.z + h.w;
    part[t] = s;
    __syncthreads();
    for (int off = 1; off < 256; off <<= 1) {
        int v = (t >= off) ? part[t - off] : 0;
        __syncthreads();
        part[t] += v;
        __syncthreads();
    }
    int ex = part[t] - s;
    if (g < NN) {
        int4 o;
        o.x = ex;
        o.y = ex + h.x;
        o.z = ex + h.x + h.y;
        o.w = ex + h.x + h.y + h.z;
        *(int4*)(offsets + g) = o;
    }
    if (t == 255) bsum[b] = part[255];
}

// phase B: add block-prefix base, mirror into cursor, write offsets[NN]
__global__ __launch_bounds__(256) void k_scanB(const int* __restrict__ bsum,
                                               int* __restrict__ offsets,
                                               int* __restrict__ cursor) {
    __shared__ int sbase, stot;
    int t = threadIdx.x, b = blockIdx.x;
    if (t == 0) {
        int acc = 0, base = 0;
        for (int i = 0; i < SCAN_BLK; i++) {
            if (i == b) base = acc;
            acc += bsum[i];
        }
        sbase = base;
        stot = acc;
    }
    __syncthreads();
    int base = sbase;
    int g = b * SCAN_ELEM + t * 4;
    if (g < NN) {
        int4 o = *(const int4*)(offsets + g);
        o.x += base; o.y += base; o.z += base; o.w += base;
        *(int4*)(offsets + g) = o;
        *(int4*)(cursor + g) = o;
    }
    if (b == SCAN_BLK - 1 && t == 0) offsets[NN] = stot;
}

__global__ __launch_bounds__(256) void k_escatter(const int* __restrict__ esrc,
                                                  const int* __restrict__ edst,
                                                  int* __restrict__ cursor,
                                                  unsigned int* __restrict__ recs) {
    int e = blockIdx.x * blockDim.x + threadIdx.x;
    if (e >= RR * EE) return;
    int r = e / EE;
    int d = edst[e];
    int pos = atomicAdd(&cursor[d], 1);
    recs[pos] = (unsigned int)esrc[e] | ((unsigned int)r << 16);
}

// one wave per dst node; per-wave weight table in LDS; 4-edge unrolled
// (round-1 configuration: measured best; later persistent/8-batch variants
// were neutral-to-negative -- gather is L2-fill bound at ~64 us, FETCH ~=
// 8 XCDs x xb working set, insensitive to scheduling structure)
__global__ __launch_bounds__(256) void k_gather(const ushort_t* __restrict__ xb,
                                                const float* __restrict__ coeff,
                                                const int* __restrict__ deg,
                                                const int* __restrict__ offsets,
                                                const unsigned int* __restrict__ recs,
                                                ushort_t* __restrict__ vb) {
    __shared__ float wtab[4][64];
    int lane = threadIdx.x & 63;
    int wv   = threadIdx.x >> 6;
    int n    = __builtin_amdgcn_readfirstlane(blockIdx.x * 4 + wv);

    {   // wtab[wv][r*4+b] = coeff[r*4+b] / max(deg[r][n],1)
        int r  = lane >> 2;
        int dg = deg[r * NN + n];
        float inv = 1.0f / (float)(dg > 0 ? dg : 1);
        wtab[wv][lane] = coeff[lane] * inv;
    }

    int beg = offsets[n], end = offsets[n + 1];
    f32x2 a[4][2];
#pragma unroll
    for (int b = 0; b < 4; b++) { a[b][0] = (f32x2){0,0}; a[b][1] = (f32x2){0,0}; }

    const float* wrow = &wtab[wv][0];
    const ushort_t* xl = xb + lane * 4;

    auto acc_edge = [&](uint2 u, float4 w) {
        f32x2 lo, hi;
        lo.x = __builtin_bit_cast(float, u.x << 16);
        lo.y = __builtin_bit_cast(float, u.x & 0xFFFF0000u);
        hi.x = __builtin_bit_cast(float, u.y << 16);
        hi.y = __builtin_bit_cast(float, u.y & 0xFFFF0000u);
        a[0][0] = lo * (f32x2){w.x, w.x} + a[0][0];
        a[0][1] = hi * (f32x2){w.x, w.x} + a[0][1];
        a[1][0] = lo * (f32x2){w.y, w.y} + a[1][0];
        a[1][1] = hi * (f32x2){w.y, w.y} + a[1][1];
        a[2][0] = lo * (f32x2){w.z, w.z} + a[2][0];
        a[2][1] = hi * (f32x2){w.z, w.z} + a[2][1];
        a[3][0] = lo * (f32x2){w.w, w.w} + a[3][0];
        a[3][1] = hi * (f32x2){w.w, w.w} + a[3][1];
    };

    int ei = beg;
    for (; ei + 4 <= end; ei += 4) {
        unsigned int r0 = recs[ei + 0];
        unsigned int r1 = recs[ei + 1];
        unsigned int r2 = recs[ei + 2];
        unsigned int r3 = recs[ei + 3];
        uint2 u0 = *(const uint2*)(xl + (size_t)(r0 & 0xFFFFu) * DD);
        uint2 u1 = *(const uint2*)(xl + (size_t)(r1 & 0xFFFFu) * DD);
        uint2 u2 = *(const uint2*)(xl + (size_t)(r2 & 0xFFFFu) * DD);
        uint2 u3 = *(const uint2*)(xl + (size_t)(r3 & 0xFFFFu) * DD);
        float4 w0 = *(const float4*)&wrow[(r0 >> 16) * 4];
        float4 w1 = *(const float4*)&wrow[(r1 >> 16) * 4];
        float4 w2 = *(const float4*)&wrow[(r2 >> 16) * 4];
        float4 w3 = *(const float4*)&wrow[(r3 >> 16) * 4];
        acc_edge(u0, w0);
        acc_edge(u1, w1);
        acc_edge(u2, w2);
        acc_edge(u3, w3);
    }
    for (; ei < end; ei++) {
        unsigned int r0 = recs[ei];
        uint2 u0 = *(const uint2*)(xl + (size_t)(r0 & 0xFFFFu) * DD);
        float4 w0 = *(const float4*)&wrow[(r0 >> 16) * 4];
        acc_edge(u0, w0);
    }

    ushort_t* vr = vb + (size_t)n * (NB * DD) + lane * 4;
#pragma unroll
    for (int b = 0; b < 4; b++) {
        ushort4 o;
        o.x = f2bf(a[b][0].x); o.y = f2bf(a[b][0].y);
        o.z = f2bf(a[b][1].x); o.w = f2bf(a[b][1].y);
        *(ushort4*)(vr + b * DD) = o;
    }
}

// MFMA GEMM: out[40000][256] = relu([vb | xb] @ Bt^T + bias)
// m97 structure: 128x128 block tile, 4 waves each 64x64 (4x4 frags of
// 16x16x32 -> 16 MFMA : 8 ds_read_b128), double-buffered LDS staged via
// global_load_lds width-16 (no ds_write, no VGPR round-trip). LDS dest is
// forced linear (DMA writes base+lane*16), so the bank-conflict swizzle
// chunk' = q ^ ((row>>2)&3) is applied by PRE-SWIZZLING the per-lane GLOBAL
// source chunk (both-sides-or-neither).
// T1: 1-D grid of GEMM_NWG=626 with bijective XCD-chunked swizzle
// (chunks 79,79,78x6); consecutive wgids within an XCD chunk are the two
// col-blocks of the SAME A row-panel -> 327KB A-panel fetched once per XCD.
__global__ __launch_bounds__(256) void k_gemm(const ushort_t* __restrict__ vb,
                                              const ushort_t* __restrict__ xb,
                                              const ushort_t* __restrict__ Bt,
                                              const float* __restrict__ bias,
                                              float* __restrict__ out) {
    __shared__ __align__(16) ushort_t As[2][BM * BK];   // 2 x 8 KB
    __shared__ __align__(16) ushort_t Bs[2][BN * BK];   // 2 x 8 KB
    int tid  = threadIdx.x;
    int lane = tid & 63;
    int w    = tid >> 6;
    int wr   = w >> 1, wc = w & 1;     // wave tile: rows wr*64.., cols wc*64..

    // XCD-chunked bijective swizzle: nwg=626, 8 XCDs -> q=78, rem=2
    int bid  = blockIdx.x;
    int xcd  = bid & 7;
    int lin  = bid >> 3;
    int wgid = (xcd < 2 ? xcd * 79 : 158 + (xcd - 2) * 78) + lin;
    int rowbase = (wgid >> 1) * BM;    // 313 row-panels; tail rows clamped
    int nbase   = (wgid & 1) * BN;
    int ml = lane & 15, q = lane >> 4;

    // staging: thread t covers LDS slot (row = t>>2, chunk = t&3); source
    // chunk pre-swizzled g = (t&3) ^ ((row>>2)&3)  [(t>>4)&3 == (srow>>2)&3]
    int srow  = tid >> 2;
    int g     = (tid & 3) ^ ((tid >> 4) & 3);
    int wbase = __builtin_amdgcn_readfirstlane(w << 10);   // wave base within 4KB round

    int arow0 = rowbase + srow;       if (arow0 >= NN) arow0 = NN - 1;
    int arow1 = rowbase + 64 + srow;  if (arow1 >= NN) arow1 = NN - 1;
    const ushort_t* pvA0 = vb + (size_t)arow0 * (NB * DD) + g * 8;
    const ushort_t* pvA1 = vb + (size_t)arow1 * (NB * DD) + g * 8;
    const ushort_t* pxA0 = xb + (size_t)arow0 * DD + g * 8;
    const ushort_t* pxA1 = xb + (size_t)arow1 * DD + g * 8;
    const ushort_t* pB0  = Bt + (size_t)(nbase + srow) * KTOT + g * 8;
    const ushort_t* pB1  = Bt + (size_t)(nbase + 64 + srow) * KTOT + g * 8;

    f32x4 acc[4][4];
#pragma unroll
    for (int i = 0; i < 4; i++)
#pragma unroll
        for (int j = 0; j < 4; j++) acc[i][j] = (f32x4){0, 0, 0, 0};

    // fragment read offsets (swizzled, ushort units)
    int aoff[4], boff[4];
#pragma unroll
    for (int i = 0; i < 4; i++) {
        int m = wr * 64 + i * 16 + ml;
        aoff[i] = m * BK + ((q ^ ((m >> 2) & 3)) * 8);
    }
#pragma unroll
    for (int j = 0; j < 4; j++) {
        int n = wc * 64 + j * 16 + ml;
        boff[j] = n * BK + ((q ^ ((n >> 2) & 3)) * 8);
    }

    auto stage = [&](int s, int kb) {
        const ushort_t* a0 = (kb < NB * DD) ? pvA0 + kb : pxA0 + (kb - NB * DD);
        const ushort_t* a1 = (kb < NB * DD) ? pvA1 + kb : pxA1 + (kb - NB * DD);
        char* ab = (char*)&As[s][0] + wbase;
        char* bb = (char*)&Bs[s][0] + wbase;
        gll16(a0,       ab);           // A rows   0..63  of tile
        gll16(a1,       ab + 4096);    // A rows  64..127
        gll16(pB0 + kb, bb);           // B rows   0..63
        gll16(pB1 + kb, bb + 4096);    // B rows  64..127
    };

    stage(0, 0);
    asm volatile("s_waitcnt vmcnt(0)" ::: "memory");
    __syncthreads();

    for (int it = 0; it < NITER; ++it) {
        int cur = it & 1;
        if (it + 1 < NITER) stage(cur ^ 1, (it + 1) * BK);   // overlaps compute
        bf16x8 af[4], bf[4];
#pragma unroll
        for (int i = 0; i < 4; i++) af[i] = *(const bf16x8*)&As[cur][aoff[i]];
#pragma unroll
        for (int j = 0; j < 4; j++) bf[j] = *(const bf16x8*)&Bs[cur][boff[j]];
#pragma unroll
        for (int i = 0; i < 4; i++)
#pragma unroll
            for (int j = 0; j < 4; j++)
                acc[i][j] = __builtin_amdgcn_mfma_f32_16x16x32_bf16(af[i], bf[j], acc[i][j], 0, 0, 0);
        asm volatile("s_waitcnt vmcnt(0)" ::: "memory");
        __syncthreads();
    }

    // epilogue: C layout col=lane&15, row=(lane>>4)*4+reg; predicate M-tail
#pragma unroll
    for (int i = 0; i < 4; i++) {
#pragma unroll
        for (int r = 0; r < 4; r++) {
            int ng = rowbase + wr * 64 + i * 16 + q * 4 + r;
            if (ng < NN) {
#pragma unroll
                for (int j = 0; j < 4; j++) {
                    int o = nbase + wc * 64 + j * 16 + ml;
                    float vv = acc[i][j][r] + bias[o];
                    out[(size_t)ng * DD + o] = fmaxf(vv, 0.0f);
                }
            }
        }
    }
}

extern "C" void kernel_launch(void* const* d_in, const int* in_sizes, int n_in,
                              void* d_out, int out_size, void* d_ws, size_t ws_size,
                              hipStream_t stream) {
    const float* x     = (const float*)d_in[0];
    const float* bases = (const float*)d_in[1];
    const float* coeff = (const float*)d_in[2];
    const float* lw    = (const float*)d_in[3];
    const float* bias  = (const float*)d_in[4];
    const int*   esrc  = (const int*)d_in[5];
    const int*   edst  = (const int*)d_in[6];
    float* out = (float*)d_out;

    char* ws = (char*)d_ws;
    ushort_t*     vb      = (ushort_t*)(ws);
    ushort_t*     xb      = (ushort_t*)(ws + 81920000);
    ushort_t*     Bt      = (ushort_t*)(ws + 102400000);
    int*          deg     = (int*)(ws + 103055360);
    int*          offsets = (int*)(ws + 105775360);
    int*          cursor  = (int*)(ws + 105935376);
    unsigned int* recs    = (unsigned int*)(ws + 106095376);
    int*          bsum    = (int*)(ws + 109295376);

    hipMemsetAsync(deg, 0, (size_t)RR * NN * sizeof(int), stream);

    int ne = RR * EE;
    k_prep<<<CAST_BLKS + DEG_BLKS, 256, 0, stream>>>(x, bases, lw, edst, xb, Bt, deg);
    k_scanA<<<SCAN_BLK, 256, 0, stream>>>(deg, offsets, bsum);
    k_scanB<<<SCAN_BLK, 256, 0, stream>>>(bsum, offsets, cursor);
    k_escatter<<<(ne + 255) / 256, 256, 0, stream>>>(esrc, edst, cursor, recs);
    k_gather<<<NN / 4, 256, 0, stream>>>(xb, coeff, deg, offsets, recs, vb);
    k_gemm<<<GEMM_NWG, 256, 0, stream>>>(vb, xb, Bt, bias, out);
}